// Round 1
// baseline (880.545 us; speedup 1.0000x reference)
//
#include <hip/hip_runtime.h>

#define WS_ALIGN(x) (((x) + (size_t)255) & ~(size_t)255)

// ---------- CSR build ----------
__global__ __launch_bounds__(256) void k_count(const int* __restrict__ ei, int* __restrict__ deg, int E) {
    int e = blockIdx.x * 256 + threadIdx.x;
    if (e < E) atomicAdd(&deg[ei[E + e]], 1);
}

__global__ __launch_bounds__(256) void k_block_sums(const int* __restrict__ deg, int* __restrict__ partial, int n) {
    __shared__ int sd[256];
    int i = blockIdx.x * 256 + threadIdx.x;
    sd[threadIdx.x] = (i < n) ? deg[i] : 0;
    __syncthreads();
    for (int s = 128; s > 0; s >>= 1) {
        if (threadIdx.x < s) sd[threadIdx.x] += sd[threadIdx.x + s];
        __syncthreads();
    }
    if (threadIdx.x == 0) partial[blockIdx.x] = sd[0];
}

__global__ __launch_bounds__(512) void k_scan_partial(int* __restrict__ partial, int nb) {
    __shared__ int sd[512];
    int t = threadIdx.x;
    int v = (t < nb) ? partial[t] : 0;
    sd[t] = v;
    __syncthreads();
    for (int off = 1; off < 512; off <<= 1) {
        int x = (t >= off) ? sd[t - off] : 0;
        __syncthreads();
        sd[t] += x;
        __syncthreads();
    }
    if (t < nb) partial[t] = sd[t] - v;   // exclusive
}

__global__ __launch_bounds__(256) void k_scan_blocks(const int* __restrict__ deg, const int* __restrict__ partial,
                                                     int* __restrict__ offs, int* __restrict__ cursor, int n) {
    __shared__ int sd[256];
    int t = threadIdx.x;
    int i = blockIdx.x * 256 + t;
    int v = (i < n) ? deg[i] : 0;
    sd[t] = v;
    __syncthreads();
    for (int off = 1; off < 256; off <<= 1) {
        int x = (t >= off) ? sd[t - off] : 0;
        __syncthreads();
        sd[t] += x;
        __syncthreads();
    }
    int excl = partial[blockIdx.x] + sd[t] - v;
    if (i < n) {
        offs[i] = excl;
        cursor[i] = excl;
        if (i == n - 1) offs[n] = excl + v;
    }
}

__global__ __launch_bounds__(256) void k_fill(const int* __restrict__ ei, int* __restrict__ cursor,
                                              int* __restrict__ csr_src, int* __restrict__ csr_eid, int E) {
    int e = blockIdx.x * 256 + threadIdx.x;
    if (e >= E) return;
    int s = ei[e], d = ei[E + e];
    int p = atomicAdd(&cursor[d], 1);
    csr_src[p] = s;
    csr_eid[p] = e;
}

// ---------- aggregation (one wave per node, lane = feature) ----------
__global__ __launch_bounds__(256) void k_aggr_edge(const float* __restrict__ ea, const int* __restrict__ offs,
                                                   const int* __restrict__ csr_eid, float* __restrict__ aggr, int n) {
    int wid = (blockIdx.x * 256 + threadIdx.x) >> 6;
    int lane = threadIdx.x & 63;
    if (wid >= n) return;
    int beg = offs[wid], end = offs[wid + 1];
    float s = (lane == 63) ? 1.0f : 0.0f;   // self-loop attr: one-hot last column
    int e = beg;
    for (; e + 2 <= end; e += 2) {
        int e0 = csr_eid[e], e1 = csr_eid[e + 1];
        float v0 = ea[(size_t)e0 * 64 + lane];
        float v1 = ea[(size_t)e1 * 64 + lane];
        s += v0 + v1;
    }
    if (e < end) s += ea[(size_t)csr_eid[e] * 64 + lane];
    aggr[(size_t)wid * 128 + lane] = s;
}

__global__ __launch_bounds__(256) void k_aggr_h(const float* __restrict__ h, const int* __restrict__ offs,
                                                const int* __restrict__ csr_src, float* __restrict__ aggr, int n) {
    int wid = (blockIdx.x * 256 + threadIdx.x) >> 6;
    int lane = threadIdx.x & 63;
    if (wid >= n) return;
    int beg = offs[wid], end = offs[wid + 1];
    float s = h[(size_t)wid * 64 + lane];   // self-loop
    int e = beg;
    for (; e + 2 <= end; e += 2) {
        int s0 = csr_src[e], s1 = csr_src[e + 1];
        float v0 = h[(size_t)s0 * 64 + lane];
        float v1 = h[(size_t)s1 * 64 + lane];
        s += v0 + v1;
    }
    if (e < end) s += h[(size_t)csr_src[e] * 64 + lane];
    aggr[(size_t)wid * 128 + 64 + lane] = s;
}

// ---------- fused MLP: relu(aggr@W1+b1)@W2+b2 ----------
__global__ __launch_bounds__(256) void k_mlp(const float* __restrict__ aggr, const float* __restrict__ W1,
                                             const float* __restrict__ b1, const float* __restrict__ W2,
                                             const float* __restrict__ b2, float* __restrict__ out,
                                             int n, int relu_out) {
    __shared__ float a_s[64][132];
    __shared__ float h_s[64][132];
    const int tid = threadIdx.x;
    const int row0 = blockIdx.x * 64;

    // stage 64 aggr rows into LDS
    for (int i = tid; i < 64 * 32; i += 256) {
        int r = i >> 5, c4 = (i & 31) << 2;
        float4 v = make_float4(0.f, 0.f, 0.f, 0.f);
        if (row0 + r < n) v = *(const float4*)(aggr + (size_t)(row0 + r) * 128 + c4);
        *(float4*)(&a_s[r][c4]) = v;
    }
    __syncthreads();

    const int ry = tid >> 4;   // 0..15 -> row group of 4
    const int cx = tid & 15;   // 0..15 -> col group

    // phase 1: hid = relu(a @ W1 + b1), 64x128, thread tile 4x8
    {
        const int j0 = cx * 8;
        float acc[4][8];
        float4 bb0 = *(const float4*)(b1 + j0);
        float4 bb1 = *(const float4*)(b1 + j0 + 4);
        const float* bp0 = (const float*)&bb0;
        const float* bp1 = (const float*)&bb1;
#pragma unroll
        for (int rr = 0; rr < 4; ++rr)
#pragma unroll
            for (int jj = 0; jj < 4; ++jj) { acc[rr][jj] = bp0[jj]; acc[rr][jj + 4] = bp1[jj]; }

        for (int k = 0; k < 128; k += 4) {
            float4 a0 = *(const float4*)(&a_s[ry * 4 + 0][k]);
            float4 a1 = *(const float4*)(&a_s[ry * 4 + 1][k]);
            float4 a2 = *(const float4*)(&a_s[ry * 4 + 2][k]);
            float4 a3 = *(const float4*)(&a_s[ry * 4 + 3][k]);
            const float* ap0 = (const float*)&a0;
            const float* ap1 = (const float*)&a1;
            const float* ap2 = (const float*)&a2;
            const float* ap3 = (const float*)&a3;
#pragma unroll
            for (int kk = 0; kk < 4; ++kk) {
                float4 w0 = *(const float4*)(W1 + (size_t)(k + kk) * 128 + j0);
                float4 w1 = *(const float4*)(W1 + (size_t)(k + kk) * 128 + j0 + 4);
                const float* wp0 = (const float*)&w0;
                const float* wp1 = (const float*)&w1;
                float av0 = ap0[kk], av1 = ap1[kk], av2 = ap2[kk], av3 = ap3[kk];
#pragma unroll
                for (int jj = 0; jj < 4; ++jj) {
                    acc[0][jj] += av0 * wp0[jj];  acc[0][jj + 4] += av0 * wp1[jj];
                    acc[1][jj] += av1 * wp0[jj];  acc[1][jj + 4] += av1 * wp1[jj];
                    acc[2][jj] += av2 * wp0[jj];  acc[2][jj + 4] += av2 * wp1[jj];
                    acc[3][jj] += av3 * wp0[jj];  acc[3][jj + 4] += av3 * wp1[jj];
                }
            }
        }
#pragma unroll
        for (int rr = 0; rr < 4; ++rr)
#pragma unroll
            for (int jj = 0; jj < 8; ++jj) {
                float v = acc[rr][jj];
                h_s[ry * 4 + rr][j0 + jj] = v > 0.f ? v : 0.f;
            }
    }
    __syncthreads();

    // phase 2: out = hid @ W2 + b2, 64x64, thread tile 4x4
    {
        const int j0 = cx * 4;
        float acc[4][4];
        float4 bb = *(const float4*)(b2 + j0);
        const float* bp = (const float*)&bb;
#pragma unroll
        for (int rr = 0; rr < 4; ++rr)
#pragma unroll
            for (int jj = 0; jj < 4; ++jj) acc[rr][jj] = bp[jj];

        for (int k = 0; k < 128; k += 4) {
            float4 a0 = *(const float4*)(&h_s[ry * 4 + 0][k]);
            float4 a1 = *(const float4*)(&h_s[ry * 4 + 1][k]);
            float4 a2 = *(const float4*)(&h_s[ry * 4 + 2][k]);
            float4 a3 = *(const float4*)(&h_s[ry * 4 + 3][k]);
            const float* ap0 = (const float*)&a0;
            const float* ap1 = (const float*)&a1;
            const float* ap2 = (const float*)&a2;
            const float* ap3 = (const float*)&a3;
#pragma unroll
            for (int kk = 0; kk < 4; ++kk) {
                float4 w = *(const float4*)(W2 + (size_t)(k + kk) * 64 + j0);
                const float* wp = (const float*)&w;
                float av0 = ap0[kk], av1 = ap1[kk], av2 = ap2[kk], av3 = ap3[kk];
#pragma unroll
                for (int jj = 0; jj < 4; ++jj) {
                    acc[0][jj] += av0 * wp[jj];
                    acc[1][jj] += av1 * wp[jj];
                    acc[2][jj] += av2 * wp[jj];
                    acc[3][jj] += av3 * wp[jj];
                }
            }
        }
#pragma unroll
        for (int rr = 0; rr < 4; ++rr) {
            int r = row0 + ry * 4 + rr;
            if (r < n) {
                float4 o;
                float* op = (float*)&o;
#pragma unroll
                for (int jj = 0; jj < 4; ++jj) {
                    float v = acc[rr][jj];
                    if (relu_out) v = v > 0.f ? v : 0.f;
                    op[jj] = v;
                }
                *(float4*)(out + (size_t)r * 64 + j0) = o;
            }
        }
    }
}

extern "C" void kernel_launch(void* const* d_in, const int* in_sizes, int n_in,
                              void* d_out, int out_size, void* d_ws, size_t ws_size,
                              hipStream_t stream) {
    const float* x  = (const float*)d_in[0];
    const int*   ei = (const int*)d_in[1];
    const float* ea = (const float*)d_in[2];
    const float* W1 = (const float*)d_in[3];
    const float* b1 = (const float*)d_in[4];
    const float* W2 = (const float*)d_in[5];
    const float* b2 = (const float*)d_in[6];
    const int N = in_sizes[0] / 64;
    const int E = in_sizes[1] / 2;
    const int L = in_sizes[3] / (128 * 128);

    char* ws = (char*)d_ws;
    size_t o = 0;
    auto carve = [&](size_t bytes) { char* p = ws + o; o += WS_ALIGN(bytes); return p; };
    int*   deg     = (int*)carve((size_t)N * 4);
    int*   offs    = (int*)carve(((size_t)N + 1) * 4);
    int*   cursor  = (int*)carve((size_t)N * 4);
    int*   partial = (int*)carve(512 * 4);
    int*   csr_src = (int*)carve((size_t)E * 4);
    int*   csr_eid = (int*)carve((size_t)E * 4);
    float* aggr    = (float*)carve((size_t)N * 128 * 4);
    float* h_buf   = (float*)carve((size_t)N * 64 * 4);

    hipMemsetAsync(deg, 0, (size_t)N * 4, stream);
    int gE = (E + 255) / 256;
    int nb = (N + 255) / 256;           // 391 <= 512
    k_count<<<gE, 256, 0, stream>>>(ei, deg, E);
    k_block_sums<<<nb, 256, 0, stream>>>(deg, partial, N);
    k_scan_partial<<<1, 512, 0, stream>>>(partial, nb);
    k_scan_blocks<<<nb, 256, 0, stream>>>(deg, partial, offs, cursor, N);
    k_fill<<<gE, 256, 0, stream>>>(ei, cursor, csr_src, csr_eid, E);

    int gN4 = (N + 3) / 4;
    k_aggr_edge<<<gN4, 256, 0, stream>>>(ea, offs, csr_eid, aggr, N);

    int gM = (N + 63) / 64;
    for (int l = 0; l < L; ++l) {
        const float* hin = (l == 0) ? x : h_buf;
        float* hout = (l == L - 1) ? (float*)d_out : h_buf;
        k_aggr_h<<<gN4, 256, 0, stream>>>(hin, offs, csr_src, aggr, N);
        k_mlp<<<gM, 256, 0, stream>>>(aggr, W1 + (size_t)l * 128 * 128, b1 + (size_t)l * 128,
                                      W2 + (size_t)l * 128 * 64, b2 + (size_t)l * 64,
                                      hout, N, (l < L - 1) ? 1 : 0);
    }
}

// Round 3
// 768.339 us; speedup vs baseline: 1.1460x; 1.1460x over previous
//
#include <hip/hip_runtime.h>

#define WS_ALIGN(x) (((x) + (size_t)255) & ~(size_t)255)

// ---------- CSR build ----------
__global__ __launch_bounds__(256) void k_count(const int* __restrict__ ei, int* __restrict__ deg, int E) {
    int e = blockIdx.x * 256 + threadIdx.x;
    if (e < E) atomicAdd(&deg[ei[E + e]], 1);
}

__global__ __launch_bounds__(256) void k_block_sums(const int* __restrict__ deg, int* __restrict__ partial, int n) {
    __shared__ int sd[256];
    int i = blockIdx.x * 256 + threadIdx.x;
    sd[threadIdx.x] = (i < n) ? deg[i] : 0;
    __syncthreads();
    for (int s = 128; s > 0; s >>= 1) {
        if (threadIdx.x < s) sd[threadIdx.x] += sd[threadIdx.x + s];
        __syncthreads();
    }
    if (threadIdx.x == 0) partial[blockIdx.x] = sd[0];
}

__global__ __launch_bounds__(512) void k_scan_partial(int* __restrict__ partial, int nb) {
    __shared__ int sd[512];
    int t = threadIdx.x;
    int v = (t < nb) ? partial[t] : 0;
    sd[t] = v;
    __syncthreads();
    for (int off = 1; off < 512; off <<= 1) {
        int x = (t >= off) ? sd[t - off] : 0;
        __syncthreads();
        sd[t] += x;
        __syncthreads();
    }
    if (t < nb) partial[t] = sd[t] - v;   // exclusive
}

__global__ __launch_bounds__(256) void k_scan_blocks(const int* __restrict__ deg, const int* __restrict__ partial,
                                                     int* __restrict__ offs, int* __restrict__ cursor, int n) {
    __shared__ int sd[256];
    int t = threadIdx.x;
    int i = blockIdx.x * 256 + t;
    int v = (i < n) ? deg[i] : 0;
    sd[t] = v;
    __syncthreads();
    for (int off = 1; off < 256; off <<= 1) {
        int x = (t >= off) ? sd[t - off] : 0;
        __syncthreads();
        sd[t] += x;
        __syncthreads();
    }
    int excl = partial[blockIdx.x] + sd[t] - v;
    if (i < n) {
        offs[i] = excl;
        cursor[i] = excl;
        if (i == n - 1) offs[n] = excl + v;
    }
}

__global__ __launch_bounds__(256) void k_fill(const int* __restrict__ ei, int* __restrict__ cursor,
                                              int* __restrict__ csr_src, int* __restrict__ csr_eid, int E) {
    int e = blockIdx.x * 256 + threadIdx.x;
    if (e >= E) return;
    int s = ei[e], d = ei[E + e];
    int p = atomicAdd(&cursor[d], 1);
    csr_src[p] = s;
    csr_eid[p] = e;
}

// ---------- edge-attr aggregation (layer-invariant), one wave per node ----------
__global__ __launch_bounds__(256) void k_aggr_edge(const float* __restrict__ ea, const int* __restrict__ offs,
                                                   const int* __restrict__ csr_eid, float* __restrict__ aggr_e, int n) {
    int wid = (blockIdx.x * 256 + threadIdx.x) >> 6;
    int lane = threadIdx.x & 63;
    if (wid >= n) return;
    int beg = offs[wid], end = offs[wid + 1];
    float s = (lane == 63) ? 1.0f : 0.0f;   // self-loop attr: one-hot last column
    for (int base = beg; base < end; base += 64) {
        int m = end - base;
        if (m > 64) m = 64;
        int idx = (lane < m) ? csr_eid[base + lane] : 0;
        int j = 0;
        for (; j + 4 <= m; j += 4) {
            int e0 = __shfl(idx, j), e1 = __shfl(idx, j + 1);
            int e2 = __shfl(idx, j + 2), e3 = __shfl(idx, j + 3);
            float v0 = ea[(size_t)e0 * 64 + lane];
            float v1 = ea[(size_t)e1 * 64 + lane];
            float v2 = ea[(size_t)e2 * 64 + lane];
            float v3 = ea[(size_t)e3 * 64 + lane];
            s += (v0 + v1) + (v2 + v3);
        }
        for (; j < m; ++j) s += ea[(size_t)__shfl(idx, j) * 64 + lane];
    }
    aggr_e[(size_t)wid * 64 + lane] = s;
}

// ---------- fused layer: gather-aggregate h + MLP ----------
// hin and hout MUST be distinct buffers (cross-block gather reads hin).
__global__ __launch_bounds__(256) void k_layer(const float* __restrict__ h, const float* __restrict__ aggr_e,
                                               const int* __restrict__ offs, const int* __restrict__ csr_src,
                                               const float* __restrict__ W1, const float* __restrict__ b1,
                                               const float* __restrict__ W2, const float* __restrict__ b2,
                                               float* __restrict__ out, int n, int relu_out) {
    __shared__ float a_s[64][132];
    const int tid = threadIdx.x;
    const int lane = tid & 63;
    const int wv = tid >> 6;          // 0..3
    const int row0 = blockIdx.x * 64;

    // stage precomputed edge-attr aggregation into a_s[:, 0:64]
    for (int i = tid; i < 64 * 16; i += 256) {
        int r = i >> 4, c4 = (i & 15) << 2;
        float4 v = make_float4(0.f, 0.f, 0.f, 0.f);
        if (row0 + r < n) v = *(const float4*)(aggr_e + (size_t)(row0 + r) * 64 + c4);
        *(float4*)(&a_s[r][c4]) = v;
    }

    // gather-aggregate h into a_s[:, 64:128]; wave wv owns rows [wv*16, wv*16+16)
    for (int i = 0; i < 16; ++i) {
        int r = wv * 16 + i;
        int node = row0 + r;
        float s = 0.f;
        if (node < n) {
            s = h[(size_t)node * 64 + lane];   // self-loop
            int beg = offs[node], end = offs[node + 1];
            for (int base = beg; base < end; base += 64) {
                int m = end - base;
                if (m > 64) m = 64;
                int idx = (lane < m) ? csr_src[base + lane] : 0;
                int j = 0;
                for (; j + 4 <= m; j += 4) {
                    int s0 = __shfl(idx, j), s1 = __shfl(idx, j + 1);
                    int s2 = __shfl(idx, j + 2), s3 = __shfl(idx, j + 3);
                    float v0 = h[(size_t)s0 * 64 + lane];
                    float v1 = h[(size_t)s1 * 64 + lane];
                    float v2 = h[(size_t)s2 * 64 + lane];
                    float v3 = h[(size_t)s3 * 64 + lane];
                    s += (v0 + v1) + (v2 + v3);
                }
                for (; j < m; ++j) s += h[(size_t)__shfl(idx, j) * 64 + lane];
            }
        }
        a_s[r][64 + lane] = s;
    }
    __syncthreads();

    const int ry = tid >> 4;   // 0..15 -> row group of 4
    const int cx = tid & 15;   // 0..15 -> col group

    // phase 1: hid = relu(a @ W1 + b1), 64x128, thread tile 4x8 (held in acc)
    float acc[4][8];
    {
        const int j0 = cx * 8;
        float4 bb0 = *(const float4*)(b1 + j0);
        float4 bb1 = *(const float4*)(b1 + j0 + 4);
        const float* bp0 = (const float*)&bb0;
        const float* bp1 = (const float*)&bb1;
#pragma unroll
        for (int rr = 0; rr < 4; ++rr)
#pragma unroll
            for (int jj = 0; jj < 4; ++jj) { acc[rr][jj] = bp0[jj]; acc[rr][jj + 4] = bp1[jj]; }

        for (int k = 0; k < 128; k += 4) {
            float4 a0 = *(const float4*)(&a_s[ry * 4 + 0][k]);
            float4 a1 = *(const float4*)(&a_s[ry * 4 + 1][k]);
            float4 a2 = *(const float4*)(&a_s[ry * 4 + 2][k]);
            float4 a3 = *(const float4*)(&a_s[ry * 4 + 3][k]);
            const float* ap0 = (const float*)&a0;
            const float* ap1 = (const float*)&a1;
            const float* ap2 = (const float*)&a2;
            const float* ap3 = (const float*)&a3;
#pragma unroll
            for (int kk = 0; kk < 4; ++kk) {
                float4 w0 = *(const float4*)(W1 + (size_t)(k + kk) * 128 + j0);
                float4 w1 = *(const float4*)(W1 + (size_t)(k + kk) * 128 + j0 + 4);
                const float* wp0 = (const float*)&w0;
                const float* wp1 = (const float*)&w1;
                float av0 = ap0[kk], av1 = ap1[kk], av2 = ap2[kk], av3 = ap3[kk];
#pragma unroll
                for (int jj = 0; jj < 4; ++jj) {
                    acc[0][jj] += av0 * wp0[jj];  acc[0][jj + 4] += av0 * wp1[jj];
                    acc[1][jj] += av1 * wp0[jj];  acc[1][jj + 4] += av1 * wp1[jj];
                    acc[2][jj] += av2 * wp0[jj];  acc[2][jj + 4] += av2 * wp1[jj];
                    acc[3][jj] += av3 * wp0[jj];  acc[3][jj + 4] += av3 * wp1[jj];
                }
            }
        }
    }
    __syncthreads();   // all a_s reads done -> safe to overwrite with hidden

    {
        const int j0 = cx * 8;
#pragma unroll
        for (int rr = 0; rr < 4; ++rr)
#pragma unroll
            for (int jj = 0; jj < 8; ++jj) {
                float v = acc[rr][jj];
                a_s[ry * 4 + rr][j0 + jj] = v > 0.f ? v : 0.f;
            }
    }
    __syncthreads();

    // phase 2: out = hid @ W2 + b2, 64x64, thread tile 4x4
    {
        const int j0 = cx * 4;
        float acc2[4][4];
        float4 bb = *(const float4*)(b2 + j0);
        const float* bp = (const float*)&bb;
#pragma unroll
        for (int rr = 0; rr < 4; ++rr)
#pragma unroll
            for (int jj = 0; jj < 4; ++jj) acc2[rr][jj] = bp[jj];

        for (int k = 0; k < 128; k += 4) {
            float4 a0 = *(const float4*)(&a_s[ry * 4 + 0][k]);
            float4 a1 = *(const float4*)(&a_s[ry * 4 + 1][k]);
            float4 a2 = *(const float4*)(&a_s[ry * 4 + 2][k]);
            float4 a3 = *(const float4*)(&a_s[ry * 4 + 3][k]);
            const float* ap0 = (const float*)&a0;
            const float* ap1 = (const float*)&a1;
            const float* ap2 = (const float*)&a2;
            const float* ap3 = (const float*)&a3;
#pragma unroll
            for (int kk = 0; kk < 4; ++kk) {
                float4 w = *(const float4*)(W2 + (size_t)(k + kk) * 64 + j0);
                const float* wp = (const float*)&w;
                float av0 = ap0[kk], av1 = ap1[kk], av2 = ap2[kk], av3 = ap3[kk];
#pragma unroll
                for (int jj = 0; jj < 4; ++jj) {
                    acc2[0][jj] += av0 * wp[jj];
                    acc2[1][jj] += av1 * wp[jj];
                    acc2[2][jj] += av2 * wp[jj];
                    acc2[3][jj] += av3 * wp[jj];
                }
            }
        }
#pragma unroll
        for (int rr = 0; rr < 4; ++rr) {
            int r = row0 + ry * 4 + rr;
            if (r < n) {
                float4 o;
                float* op = (float*)&o;
#pragma unroll
                for (int jj = 0; jj < 4; ++jj) {
                    float v = acc2[rr][jj];
                    if (relu_out) v = v > 0.f ? v : 0.f;
                    op[jj] = v;
                }
                *(float4*)(out + (size_t)r * 64 + j0) = o;
            }
        }
    }
}

extern "C" void kernel_launch(void* const* d_in, const int* in_sizes, int n_in,
                              void* d_out, int out_size, void* d_ws, size_t ws_size,
                              hipStream_t stream) {
    const float* x  = (const float*)d_in[0];
    const int*   ei = (const int*)d_in[1];
    const float* ea = (const float*)d_in[2];
    const float* W1 = (const float*)d_in[3];
    const float* b1 = (const float*)d_in[4];
    const float* W2 = (const float*)d_in[5];
    const float* b2 = (const float*)d_in[6];
    const int N = in_sizes[0] / 64;
    const int E = in_sizes[1] / 2;
    const int L = in_sizes[3] / (128 * 128);

    char* ws = (char*)d_ws;
    size_t o = 0;
    auto carve = [&](size_t bytes) { char* p = ws + o; o += WS_ALIGN(bytes); return p; };
    int*   deg     = (int*)carve((size_t)N * 4);
    int*   offs    = (int*)carve(((size_t)N + 1) * 4);
    int*   cursor  = (int*)carve((size_t)N * 4);
    int*   partial = (int*)carve(512 * 4);
    int*   csr_src = (int*)carve((size_t)E * 4);
    int*   csr_eid = (int*)carve((size_t)E * 4);
    float* aggr_e  = (float*)carve((size_t)N * 64 * 4);
    float* hA      = (float*)carve((size_t)N * 64 * 4);   // ping-pong: gather reads
    float* hB      = (float*)carve((size_t)N * 64 * 4);   // and MLP writes must not alias

    hipMemsetAsync(deg, 0, (size_t)N * 4, stream);
    int gE = (E + 255) / 256;
    int nb = (N + 255) / 256;           // 391 <= 512
    k_count<<<gE, 256, 0, stream>>>(ei, deg, E);
    k_block_sums<<<nb, 256, 0, stream>>>(deg, partial, N);
    k_scan_partial<<<1, 512, 0, stream>>>(partial, nb);
    k_scan_blocks<<<nb, 256, 0, stream>>>(deg, partial, offs, cursor, N);
    k_fill<<<gE, 256, 0, stream>>>(ei, cursor, csr_src, csr_eid, E);

    int gN4 = (N + 3) / 4;
    k_aggr_edge<<<gN4, 256, 0, stream>>>(ea, offs, csr_eid, aggr_e, N);

    int gM = (N + 63) / 64;
    for (int l = 0; l < L; ++l) {
        const float* hin = (l == 0) ? x : ((l & 1) ? hA : hB);
        float* hout = (l == L - 1) ? (float*)d_out : ((l & 1) ? hB : hA);
        k_layer<<<gM, 256, 0, stream>>>(hin, aggr_e, offs, csr_src,
                                        W1 + (size_t)l * 128 * 128, b1 + (size_t)l * 128,
                                        W2 + (size_t)l * 128 * 64, b2 + (size_t)l * 64,
                                        hout, N, (l < L - 1) ? 1 : 0);
    }
}

// Round 4
// 646.206 us; speedup vs baseline: 1.3626x; 1.1890x over previous
//
#include <hip/hip_runtime.h>

typedef unsigned int uint;
typedef unsigned short ushort;

#define WS_ALIGN(x) (((x) + (size_t)255) & ~(size_t)255)

typedef __attribute__((ext_vector_type(8))) short short8;
typedef __attribute__((ext_vector_type(4))) float f32x4;

__device__ __forceinline__ ushort f2bf(float f) {
    uint u = __builtin_bit_cast(uint, f);
    u = (u + 0x7fffu + ((u >> 16) & 1u)) >> 16;   // RNE
    return (ushort)u;
}
__device__ __forceinline__ float bflo(uint u) { return __builtin_bit_cast(float, u << 16); }
__device__ __forceinline__ float bfhi(uint u) { return __builtin_bit_cast(float, u & 0xffff0000u); }

// ---------- CSR build ----------
__global__ __launch_bounds__(256) void k_count(const int* __restrict__ ei, int* __restrict__ deg, int E) {
    int e = blockIdx.x * 256 + threadIdx.x;
    if (e < E) atomicAdd(&deg[ei[E + e]], 1);
}

__global__ __launch_bounds__(256) void k_block_sums(const int* __restrict__ deg, int* __restrict__ partial, int n) {
    __shared__ int sd[256];
    int i = blockIdx.x * 256 + threadIdx.x;
    sd[threadIdx.x] = (i < n) ? deg[i] : 0;
    __syncthreads();
    for (int s = 128; s > 0; s >>= 1) {
        if (threadIdx.x < s) sd[threadIdx.x] += sd[threadIdx.x + s];
        __syncthreads();
    }
    if (threadIdx.x == 0) partial[blockIdx.x] = sd[0];
}

__global__ __launch_bounds__(512) void k_scan_partial(int* __restrict__ partial, int nb) {
    __shared__ int sd[512];
    int t = threadIdx.x;
    int v = (t < nb) ? partial[t] : 0;
    sd[t] = v;
    __syncthreads();
    for (int off = 1; off < 512; off <<= 1) {
        int x = (t >= off) ? sd[t - off] : 0;
        __syncthreads();
        sd[t] += x;
        __syncthreads();
    }
    if (t < nb) partial[t] = sd[t] - v;   // exclusive
}

__global__ __launch_bounds__(256) void k_scan_blocks(const int* __restrict__ deg, const int* __restrict__ partial,
                                                     int* __restrict__ offs, int* __restrict__ cursor, int n) {
    __shared__ int sd[256];
    int t = threadIdx.x;
    int i = blockIdx.x * 256 + t;
    int v = (i < n) ? deg[i] : 0;
    sd[t] = v;
    __syncthreads();
    for (int off = 1; off < 256; off <<= 1) {
        int x = (t >= off) ? sd[t - off] : 0;
        __syncthreads();
        sd[t] += x;
        __syncthreads();
    }
    int excl = partial[blockIdx.x] + sd[t] - v;
    if (i < n) {
        offs[i] = excl;
        cursor[i] = excl;
        if (i == n - 1) offs[n] = excl + v;
    }
}

__global__ __launch_bounds__(256) void k_fill(const int* __restrict__ ei, int* __restrict__ cursor,
                                              int* __restrict__ csr_src, int* __restrict__ csr_eid, int E) {
    int e = blockIdx.x * 256 + threadIdx.x;
    if (e >= E) return;
    int s = ei[e], d = ei[E + e];
    int p = atomicAdd(&cursor[d], 1);
    csr_src[p] = s;
    csr_eid[p] = e;
}

// ---------- fp32 -> bf16 converters ----------
__global__ __launch_bounds__(256) void k_cvt_bf16(const float4* __restrict__ in, ushort4* __restrict__ out, int n4) {
    int i = blockIdx.x * 256 + threadIdx.x;
    if (i < n4) {
        float4 v = in[i];
        ushort4 o;
        o.x = f2bf(v.x); o.y = f2bf(v.y); o.z = f2bf(v.z); o.w = f2bf(v.w);
        out[i] = o;
    }
}

// Wt[l][nn][kk] = bf16(W[l][kk][nn]);  K fixed at 128, cols = N-dim of W
__global__ __launch_bounds__(256) void k_wt(const float* __restrict__ W, ushort* __restrict__ Wt, int total, int cols) {
    int i = blockIdx.x * 256 + threadIdx.x;
    if (i >= total) return;
    int kk = i & 127;
    int rem = i >> 7;          // l*cols + nn
    int nn = rem % cols;
    int l = rem / cols;
    Wt[i] = f2bf(W[((size_t)(l * 128 + kk)) * cols + nn]);
}

// ---------- edge-attr aggregation (layer-invariant), one wave per node, bf16 out ----------
__global__ __launch_bounds__(256) void k_aggr_edge(const float* __restrict__ ea, const int* __restrict__ offs,
                                                   const int* __restrict__ csr_eid, ushort* __restrict__ aggr_e, int n) {
    int wid = (blockIdx.x * 256 + threadIdx.x) >> 6;
    int lane = threadIdx.x & 63;
    if (wid >= n) return;
    int beg = offs[wid], end = offs[wid + 1];
    float s = (lane == 63) ? 1.0f : 0.0f;   // self-loop attr: one-hot last column
    for (int base = beg; base < end; base += 64) {
        int m = end - base;
        if (m > 64) m = 64;
        int idx = (lane < m) ? csr_eid[base + lane] : 0;
        int j = 0;
        for (; j + 4 <= m; j += 4) {
            int e0 = __shfl(idx, j), e1 = __shfl(idx, j + 1);
            int e2 = __shfl(idx, j + 2), e3 = __shfl(idx, j + 3);
            float v0 = ea[(size_t)e0 * 64 + lane];
            float v1 = ea[(size_t)e1 * 64 + lane];
            float v2 = ea[(size_t)e2 * 64 + lane];
            float v3 = ea[(size_t)e3 * 64 + lane];
            s += (v0 + v1) + (v2 + v3);
        }
        for (; j < m; ++j) s += ea[(size_t)__shfl(idx, j) * 64 + lane];
    }
    aggr_e[(size_t)wid * 64 + lane] = f2bf(s);
}

// ---------- fused layer: bf16 gather-aggregate + MFMA MLP, barrier-free ----------
// Each wave owns 16 rows end-to-end. hin/hout must be distinct buffers.
__global__ __launch_bounds__(256) void k_layer(const ushort* __restrict__ h,      // bf16 [n][64]
                                               const ushort* __restrict__ aggr_e, // bf16 [n][64]
                                               const int* __restrict__ offs, const int* __restrict__ csr_src,
                                               const ushort* __restrict__ W1t,    // bf16 [128][128] (n-major)
                                               const float* __restrict__ b1,
                                               const ushort* __restrict__ W2t,    // bf16 [64][128]  (n-major)
                                               const float* __restrict__ b2,
                                               float* __restrict__ outf,          // fp32 out (last layer) or null
                                               ushort* __restrict__ outh,         // bf16 out (+relu) or null
                                               int n) {
    __shared__ ushort a_s[64][136];     // [row][128 bf16 aggr features], pad to 136
    __shared__ ushort hid_s[64][136];
    const int tid = threadIdx.x;
    const int lane = tid & 63;
    const int wv = tid >> 6;            // 0..3
    const int row0 = blockIdx.x * 64;
    const int mrow0 = wv * 16;          // wave-owned row block inside the tile

    // ---- stage aggr_e into a_s[:, 0:64] (own rows) ----
    {
        int rr = lane >> 4;             // 0..3
        int c = (lane & 15) * 4;        // ushort4 granularity
        for (int i = 0; i < 4; ++i) {
            int r = mrow0 + i * 4 + rr;
            int node = row0 + r;
            ushort4 v = make_ushort4(0, 0, 0, 0);
            if (node < n) v = *(const ushort4*)(aggr_e + (size_t)node * 64 + c);
            *(ushort4*)(&a_s[r][c]) = v;
        }
    }

    // ---- gather-aggregate h into a_s[:, 64:128]; two edges per wave-load ----
    {
        const uint* h32 = (const uint*)h;   // [n][32] packed bf16 pairs
        const int half = lane >> 5;         // 0: even edge, 1: odd edge
        const int c = lane & 31;            // feature pair index
        for (int i = 0; i < 16; ++i) {
            int node = row0 + mrow0 + i;
            float s0 = 0.f, s1 = 0.f;
            if (node < n) {
                if (half == 0) {            // self-loop (counted once)
                    uint u = h32[(size_t)node * 32 + c];
                    s0 = bflo(u); s1 = bfhi(u);
                }
                int beg = offs[node], end = offs[node + 1];
                for (int base = beg; base < end; base += 64) {
                    int m = end - base;
                    if (m > 64) m = 64;
                    int idx = (lane < m) ? csr_src[base + lane] : 0;
                    int j = 0;
                    for (; j + 8 <= m; j += 8) {   // 8 edges in flight (4 per half)
                        int r0 = __shfl(idx, j + half);
                        int r1 = __shfl(idx, j + 2 + half);
                        int r2 = __shfl(idx, j + 4 + half);
                        int r3 = __shfl(idx, j + 6 + half);
                        uint u0 = h32[(size_t)r0 * 32 + c];
                        uint u1 = h32[(size_t)r1 * 32 + c];
                        uint u2 = h32[(size_t)r2 * 32 + c];
                        uint u3 = h32[(size_t)r3 * 32 + c];
                        s0 += (bflo(u0) + bflo(u1)) + (bflo(u2) + bflo(u3));
                        s1 += (bfhi(u0) + bfhi(u1)) + (bfhi(u2) + bfhi(u3));
                    }
                    for (; j + 2 <= m; j += 2) {
                        int r = __shfl(idx, j + half);
                        uint u = h32[(size_t)r * 32 + c];
                        s0 += bflo(u); s1 += bfhi(u);
                    }
                    if (j < m) {                   // single tail edge -> half 0 only
                        int r = __shfl(idx, j);
                        if (half == 0) {
                            uint u = h32[(size_t)r * 32 + c];
                            s0 += bflo(u); s1 += bfhi(u);
                        }
                    }
                }
            }
            // combine halves, then half 0 writes the packed pair
            s0 += __shfl(s0, lane ^ 32);
            s1 += __shfl(s1, lane ^ 32);
            if (half == 0) {
                uint packed = (uint)f2bf(s0) | ((uint)f2bf(s1) << 16);
                *(uint*)(&a_s[mrow0 + i][64 + c * 2]) = packed;
            }
        }
    }
    // no __syncthreads: each wave reads only the rows it wrote (LDS is in-order per wave)

    const int arow = mrow0 + (lane & 15);
    const int koff = (lane >> 4) * 8;
    const int drow = mrow0 + (lane >> 4) * 4;

    // ---- phase 1: hid = relu(a @ W1 + b1), 64x128 ----
    f32x4 acc[8];
#pragma unroll
    for (int nt = 0; nt < 8; ++nt) acc[nt] = (f32x4)(0.f);
    for (int ks = 0; ks < 4; ++ks) {
        short8 af = *(const short8*)(&a_s[arow][ks * 32 + koff]);
#pragma unroll
        for (int nt = 0; nt < 8; ++nt) {
            short8 bf = *(const short8*)(W1t + (size_t)(nt * 16 + (lane & 15)) * 128 + ks * 32 + koff);
            acc[nt] = __builtin_amdgcn_mfma_f32_16x16x32_bf16(af, bf, acc[nt], 0, 0, 0);
        }
    }
#pragma unroll
    for (int nt = 0; nt < 8; ++nt) {
        int col = nt * 16 + (lane & 15);
        float bias = b1[col];
#pragma unroll
        for (int r = 0; r < 4; ++r) {
            float v = acc[nt][r] + bias;
            v = v > 0.f ? v : 0.f;
            hid_s[drow + r][col] = f2bf(v);
        }
    }

    // ---- phase 2: out = hid @ W2 + b2, 64x64 ----
    f32x4 acc2[4];
#pragma unroll
    for (int nt = 0; nt < 4; ++nt) acc2[nt] = (f32x4)(0.f);
    for (int ks = 0; ks < 4; ++ks) {
        short8 af = *(const short8*)(&hid_s[arow][ks * 32 + koff]);
#pragma unroll
        for (int nt = 0; nt < 4; ++nt) {
            short8 bf = *(const short8*)(W2t + (size_t)(nt * 16 + (lane & 15)) * 128 + ks * 32 + koff);
            acc2[nt] = __builtin_amdgcn_mfma_f32_16x16x32_bf16(af, bf, acc2[nt], 0, 0, 0);
        }
    }
#pragma unroll
    for (int nt = 0; nt < 4; ++nt) {
        int col = nt * 16 + (lane & 15);
        float bias = b2[col];
#pragma unroll
        for (int r = 0; r < 4; ++r) {
            int grow = row0 + drow + r;
            if (grow < n) {
                float v = acc2[nt][r] + bias;
                if (outh) {
                    v = v > 0.f ? v : 0.f;
                    outh[(size_t)grow * 64 + col] = f2bf(v);
                } else {
                    outf[(size_t)grow * 64 + col] = v;
                }
            }
        }
    }
}

extern "C" void kernel_launch(void* const* d_in, const int* in_sizes, int n_in,
                              void* d_out, int out_size, void* d_ws, size_t ws_size,
                              hipStream_t stream) {
    const float* x  = (const float*)d_in[0];
    const int*   ei = (const int*)d_in[1];
    const float* ea = (const float*)d_in[2];
    const float* W1 = (const float*)d_in[3];
    const float* b1 = (const float*)d_in[4];
    const float* W2 = (const float*)d_in[5];
    const float* b2 = (const float*)d_in[6];
    const int N = in_sizes[0] / 64;
    const int E = in_sizes[1] / 2;
    const int L = in_sizes[3] / (128 * 128);

    char* ws = (char*)d_ws;
    size_t o = 0;
    auto carve = [&](size_t bytes) { char* p = ws + o; o += WS_ALIGN(bytes); return p; };
    int*    deg     = (int*)carve((size_t)N * 4);
    int*    offs    = (int*)carve(((size_t)N + 1) * 4);
    int*    cursor  = (int*)carve((size_t)N * 4);
    int*    partial = (int*)carve(512 * 4);
    int*    csr_src = (int*)carve((size_t)E * 4);
    int*    csr_eid = (int*)carve((size_t)E * 4);
    ushort* aggr_e  = (ushort*)carve((size_t)N * 64 * 2);
    ushort* xh      = (ushort*)carve((size_t)N * 64 * 2);
    ushort* hA      = (ushort*)carve((size_t)N * 64 * 2);
    ushort* hB      = (ushort*)carve((size_t)N * 64 * 2);
    ushort* W1t     = (ushort*)carve((size_t)L * 128 * 128 * 2);
    ushort* W2t     = (ushort*)carve((size_t)L * 64 * 128 * 2);

    hipMemsetAsync(deg, 0, (size_t)N * 4, stream);
    int gE = (E + 255) / 256;
    int nb = (N + 255) / 256;           // 391 <= 512
    k_count<<<gE, 256, 0, stream>>>(ei, deg, E);
    k_block_sums<<<nb, 256, 0, stream>>>(deg, partial, N);
    k_scan_partial<<<1, 512, 0, stream>>>(partial, nb);
    k_scan_blocks<<<nb, 256, 0, stream>>>(deg, partial, offs, cursor, N);
    k_fill<<<gE, 256, 0, stream>>>(ei, cursor, csr_src, csr_eid, E);

    // conversions (independent of CSR)
    int n4 = N * 16;                    // N*64/4
    k_cvt_bf16<<<(n4 + 255) / 256, 256, 0, stream>>>((const float4*)x, (ushort4*)xh, n4);
    int tw1 = L * 128 * 128;
    int tw2 = L * 64 * 128;
    k_wt<<<(tw1 + 255) / 256, 256, 0, stream>>>(W1, W1t, tw1, 128);
    k_wt<<<(tw2 + 255) / 256, 256, 0, stream>>>(W2, W2t, tw2, 64);

    int gN4 = (N + 3) / 4;
    k_aggr_edge<<<gN4, 256, 0, stream>>>(ea, offs, csr_eid, aggr_e, N);

    int gM = (N + 63) / 64;
    for (int l = 0; l < L; ++l) {
        const ushort* hin = (l == 0) ? xh : ((l == 1) ? hA : hB);
        float*  outf = (l == L - 1) ? (float*)d_out : nullptr;
        ushort* outh = (l == L - 1) ? nullptr : ((l == 0) ? hA : hB);
        k_layer<<<gM, 256, 0, stream>>>(hin, aggr_e, offs, csr_src,
                                        W1t + (size_t)l * 128 * 128, b1 + (size_t)l * 128,
                                        W2t + (size_t)l * 64 * 128, b2 + (size_t)l * 64,
                                        outf, outh, N);
    }
}